// Round 3
// baseline (120.359 us; speedup 1.0000x reference)
//
#include <hip/hip_runtime.h>
#include <hip/hip_fp16.h>

// MacTensorUnit — R8 (resubmit; round-2 failure was container-acquire infra,
// not kernel). Structure (R4): x3 = F(x0) with F = f∘f∘f a UNIVERSAL
// scalar map -> prep kernel tabulates F (4096 node-pair half2 entries, [-8,8]);
// kernel 2: expansion -> LDS-LUT lerp -> gate -> sum4. |x|>8: sigmoids
// saturate exactly in fp32 -> affine tails, slopes cP^3/cN^3 from runtime
// arrays.
//
// R7 (kept): BPT=4 (8 blocks/CU steady state), depth-2 register prefetch,
// plain stores (L2 write-combine), __launch_bounds__(256,8).
// R8 (theory: block SETUP ~1500cy vs ~2000cy loop work at BPT=4 — amortize):
//  a) prep kernel packs weights as float4(iw,ib,ow,ob) -> mac does 8 aligned
//     dwordx4 loads instead of 32 scalar gathers.
//  b) tail slopes precomputed in prep kernel -> mac loses make_coef entirely
//     (removes 4 sinf + ~35 VALU + angle/velocity loads per thread).
//  c) prep fused into one launch: blocks [0,16) build LUT (+slopes at i==0),
//     blocks [16,408) pack weights.

#define STEP2f    0.11110889f          // 0.33333^2
#define INV_2PI   0.15915494309189535f
#define LOG2E     1.4426950408889634f
#define LUT_N     4096
#define LUT_B     8.0f
#define LUT_SCALE 256.0f               // LUT_N / (2*LUT_B)
#define BPT       4                    // batches per thread (grid.y = 256/BPT)
#define NWS       100352               // 512*196 weight positions
#define COEF_OFF  16384                // byte offset of slopes in d_ws
#define WPACK_OFF 32768                // byte offset of packed weights in d_ws

struct MacCoef {
    float ca1, ca3, cb1, cb3;   // logistic-Phi poly, -log2e folded
    float A0r, dAr;             // angle affine, revolutions
    float V0s, dVs;             // velocity affine * STEP^2
};

__device__ __forceinline__ MacCoef make_coef(const float* angles, const float* velocity) {
    MacCoef c;
    c.ca1 = -1.5957691216f * LOG2E;
    c.ca3 = -0.0713548168f * LOG2E;
    c.cb1 = c.ca1 * 1.41421356237f;
    c.cb3 = c.ca3 * 2.82842712475f;
    c.A0r = angles[0] * INV_2PI;
    c.dAr = (angles[4] - angles[0]) * 1.25f * INV_2PI;
    c.V0s = velocity[0] * STEP2f;
    c.dVs = (velocity[4] - velocity[0]) * 1.25f * STEP2f;
    return c;
}

// one exact MAC step (R3 math: 2 exp2 + shared rcp + hw sin/cos)
__device__ __forceinline__ float mac_step(float x, const MacCoef& c) {
    float xx = x * x;
    float ua = fminf(x * fmaf(c.ca3, xx, c.ca1), 60.0f);
    float ub = fminf(x * fmaf(c.cb3, xx, c.cb1), 60.0f);
    float ea = __builtin_amdgcn_exp2f(ua);
    float eb = __builtin_amdgcn_exp2f(ub);
    float da = 1.0f + ea, db = 1.0f + eb;
    float rp = __builtin_amdgcn_rcpf(da * db);
    float sa = db * rp;                       // ngd(x)
    float sb = da * rp;                       // nerf(x)
    float r  = fmaf(c.dAr, sa, c.A0r);        // revolutions
    float v2 = fmaf(c.dVs, sb, c.V0s);
    float sn = __builtin_amdgcn_sinf(r);
    float cs = __builtin_amdgcn_cosf(r);
    return fmaf(v2, fmaf(x, sn, cs), x);
}

__device__ __forceinline__ float F3(float x, const MacCoef& c) {
    x = mac_step(x, c);
    x = mac_step(x, c);
    return mac_step(x, c);
}

// ---- prep kernel: LUT + tail slopes + packed weights, one launch ----------
__global__ __launch_bounds__(256) void prep_kernel(
    const float* __restrict__ angles, const float* __restrict__ velocity,
    const float* __restrict__ in_w,  const float* __restrict__ in_b,
    const float* __restrict__ out_w, const float* __restrict__ out_b,
    __half2* __restrict__ lut2, float* __restrict__ slopes,
    float4* __restrict__ wpack)
{
    const int b = blockIdx.x;
    if (b < 16) {
        int i = b * 256 + threadIdx.x;           // 0 .. 4095
        MacCoef c = make_coef(angles, velocity);
        float x0 = fmaf((float)i,       1.0f / LUT_SCALE, -LUT_B);
        float x1 = fmaf((float)(i + 1), 1.0f / LUT_SCALE, -LUT_B);
        lut2[i] = __halves2half2(__float2half(F3(x0, c)), __float2half(F3(x1, c)));
        if (i == 0) {
            // |x|>8 tails: sigmoids saturated -> F affine, slope cP^3/cN^3
            float snp = __builtin_amdgcn_sinf(c.A0r + c.dAr);
            float cP  = fmaf(c.V0s + c.dVs, snp, 1.0f);
            float snn = __builtin_amdgcn_sinf(c.A0r);
            float cN  = fmaf(c.V0s, snn, 1.0f);
            slopes[0] = cP * cP * cP;
            slopes[1] = cN * cN * cN;
        }
    } else {
        int s = (b - 16) * 256 + threadIdx.x;    // 0 .. 100351
        wpack[s] = make_float4(in_w[s], in_b[s], out_w[s], out_b[s]);
    }
}

// ------------- kernel 2: expansion -> LUT lerp -> gate -> sum4 -------------
__global__ __launch_bounds__(256, 8) void mac_kernel(
    const float* __restrict__ data,
    const float4* __restrict__ wpack,
    const float* __restrict__ slopes,
    const __half2* __restrict__ glut,
    float* __restrict__ out)
{
    __shared__ __half2 lut[LUT_N];               // 16 KB

    const int tid = threadIdx.x;
    // vectorized LDS fill: 4096 half2 = 1024 uint4
    {
        const uint4* src = (const uint4*)glut;
        uint4* dst = (uint4*)lut;
#pragma unroll
        for (int i = 0; i < 4; ++i) dst[tid + 256 * i] = src[tid + 256 * i];
    }

    const int t  = blockIdx.x * 256 + tid;       // 0 .. 12543 (= 256*49)
    const int os = t % 49;
    const int c  = t / 49;                       // data channel, 0..255

    // packed per-position weights for BOTH cc = 2c (e=0) and 2c+1 (e=1):
    // w[e][sf] = (iw, ib, ow, ob) at s = (2c)*196 + e*196 + sf*49 + os
    float4 w[2][4];
    {
        const float4* wq = wpack + c * 392 + os;
#pragma unroll
        for (int e = 0; e < 2; ++e)
#pragma unroll
            for (int sf = 0; sf < 4; ++sf)
                w[e][sf] = wq[e * 196 + sf * 49];
    }

    const float slopeP = slopes[0];
    const float slopeN = slopes[1];

    __syncthreads();

    const float* dptr = data + ((size_t)(blockIdx.y * BPT) * 256 + c) * 196 + os;
    float*       optr = out  + (size_t)(blockIdx.y * BPT) * 25088 + c * 98 + os;

    // depth-2 register prefetch pipeline over batches (8 dwords in flight)
    float r0[4], r1[4], r2[4];
#pragma unroll
    for (int sf = 0; sf < 4; ++sf) r0[sf] = dptr[sf * 49];
#pragma unroll
    for (int sf = 0; sf < 4; ++sf) r1[sf] = dptr[50176 + sf * 49];

#pragma unroll
    for (int k = 0; k < BPT; ++k) {
        if (k + 2 < BPT) {
            const float* dn = dptr + (size_t)(k + 2) * 50176;   // 256*196
#pragma unroll
            for (int sf = 0; sf < 4; ++sf) r2[sf] = dn[sf * 49];
        }

        float yv[2][4], tg[2][4];
#pragma unroll
        for (int sf = 0; sf < 4; ++sf) {
            float xv = r0[sf];
#pragma unroll
            for (int e = 0; e < 2; ++e) {
                float x0 = fmaf(xv, w[e][sf].x, w[e][sf].y);
                float xc = fminf(fmaxf(x0, -LUT_B), LUT_B);
                float fi = fmaf(xc, LUT_SCALE, 2048.0f);   // [0, 4096]
                int   j  = min((int)fi, LUT_N - 1);
                float fr = fi - (float)j;
                __half2 p = lut[j];                        // (F[j], F[j+1])
                float lo = __low2float(p), hi = __high2float(p);
                float v  = fmaf(fr, hi - lo, lo);          // interior F(x0)
                float dd = x0 - xc;                        // tails only
                float sl = x0 > 0.0f ? slopeP : slopeN;
                float y  = fmaf(dd, sl, v);
                yv[e][sf] = y;
                tg[e][sf] = fmaf(y, w[e][sf].z, w[e][sf].w);
            }
        }

        // gate att = 0.5*tg/(1+|tg|)+0.5, shared rcp per pair (exact)
#pragma unroll
        for (int e = 0; e < 2; ++e) {
            float acc = 0.0f;
#pragma unroll
            for (int p = 0; p < 2; ++p) {
                float t0 = tg[e][2 * p], t1 = tg[e][2 * p + 1];
                float d0 = 1.0f + fabsf(t0);
                float d1 = 1.0f + fabsf(t1);
                float rr = __builtin_amdgcn_rcpf(d0 * d1);
                acc = fmaf(yv[e][2 * p],     fmaf(0.5f * t0, d1 * rr, 0.5f), acc);
                acc = fmaf(yv[e][2 * p + 1], fmaf(0.5f * t1, d0 * rr, 0.5f), acc);
            }
            optr[(size_t)k * 25088 + e * 49] = acc;        // L2 write-combine
        }

        // rotate prefetch registers (free under full unroll)
#pragma unroll
        for (int sf = 0; sf < 4; ++sf) { r0[sf] = r1[sf]; r1[sf] = r2[sf]; }
    }
}

extern "C" void kernel_launch(void* const* d_in, const int* in_sizes, int n_in,
                              void* d_out, int out_size, void* d_ws, size_t ws_size,
                              hipStream_t stream) {
    const float* data   = (const float*)d_in[0];
    const float* in_w   = (const float*)d_in[1];
    const float* in_b   = (const float*)d_in[2];
    const float* out_w  = (const float*)d_in[3];
    const float* out_b  = (const float*)d_in[4];
    const float* angles = (const float*)d_in[5];
    const float* vel    = (const float*)d_in[6];
    float* out = (float*)d_out;

    __half2* lut    = (__half2*)d_ws;                          // 16 KB
    float*   slopes = (float*)((char*)d_ws + COEF_OFF);        // 2 floats
    float4*  wpack  = (float4*)((char*)d_ws + WPACK_OFF);      // 1.6 MB

    prep_kernel<<<dim3(16 + NWS / 256), 256, 0, stream>>>(
        angles, vel, in_w, in_b, out_w, out_b, lut, slopes, wpack);

    dim3 grid(49, 256 / BPT);                    // 49*64 blocks, (c,os) x batch
    mac_kernel<<<grid, 256, 0, stream>>>(data, wpack, slopes, lut, out);
}

// Round 4
// 119.014 us; speedup vs baseline: 1.0113x; 1.0113x over previous
//
#include <hip/hip_runtime.h>
#include <hip/hip_fp16.h>

// MacTensorUnit — R9. Structure (R4): x3 = F(x0) with F = f∘f∘f a UNIVERSAL
// scalar map -> prep kernel tabulates F (4096 node-pair half2 entries, [-8,8]);
// kernel 2: expansion -> LDS-LUT lerp -> gate -> sum4. |x|>8: sigmoids
// saturate exactly in fp32 -> affine tails, slopes cP^3/cN^3 from runtime
// arrays.
//
// R7 (kept): plain stores (L2 write-combine), __launch_bounds__(256,8).
// R8 (kept): prep packs float4(iw,ib,ow,ob) + precomputed tail slopes ->
//            mac setup is 12 wide loads, no make_coef, no sinf.
// R9 (single variable; theory: still latency/occupancy-bound — R0 measured
//     35% occupancy vs 8-block static limit; dispatch ramp + backfill skew):
//     BPT 4 -> 2. 6272 blocks, 24.5 blocks/CU through time vs 8 resident.
//     Each block front-loads its ENTIRE data set (8 dwords) + 12 setup loads,
//     computes 2 batches, dies. Shorter blocks = smoother backfill = higher
//     time-averaged occupancy. Setup doubling is cheap post-R8 (L2-hit LUT
//     refill ~3 us aggregate).

#define STEP2f    0.11110889f          // 0.33333^2
#define INV_2PI   0.15915494309189535f
#define LOG2E     1.4426950408889634f
#define LUT_N     4096
#define LUT_B     8.0f
#define LUT_SCALE 256.0f               // LUT_N / (2*LUT_B)
#define BPT       2                    // batches per thread (grid.y = 256/BPT)
#define NWS       100352               // 512*196 weight positions
#define COEF_OFF  16384                // byte offset of slopes in d_ws
#define WPACK_OFF 32768                // byte offset of packed weights in d_ws

struct MacCoef {
    float ca1, ca3, cb1, cb3;   // logistic-Phi poly, -log2e folded
    float A0r, dAr;             // angle affine, revolutions
    float V0s, dVs;             // velocity affine * STEP^2
};

__device__ __forceinline__ MacCoef make_coef(const float* angles, const float* velocity) {
    MacCoef c;
    c.ca1 = -1.5957691216f * LOG2E;
    c.ca3 = -0.0713548168f * LOG2E;
    c.cb1 = c.ca1 * 1.41421356237f;
    c.cb3 = c.ca3 * 2.82842712475f;
    c.A0r = angles[0] * INV_2PI;
    c.dAr = (angles[4] - angles[0]) * 1.25f * INV_2PI;
    c.V0s = velocity[0] * STEP2f;
    c.dVs = (velocity[4] - velocity[0]) * 1.25f * STEP2f;
    return c;
}

// one exact MAC step (R3 math: 2 exp2 + shared rcp + hw sin/cos)
__device__ __forceinline__ float mac_step(float x, const MacCoef& c) {
    float xx = x * x;
    float ua = fminf(x * fmaf(c.ca3, xx, c.ca1), 60.0f);
    float ub = fminf(x * fmaf(c.cb3, xx, c.cb1), 60.0f);
    float ea = __builtin_amdgcn_exp2f(ua);
    float eb = __builtin_amdgcn_exp2f(ub);
    float da = 1.0f + ea, db = 1.0f + eb;
    float rp = __builtin_amdgcn_rcpf(da * db);
    float sa = db * rp;                       // ngd(x)
    float sb = da * rp;                       // nerf(x)
    float r  = fmaf(c.dAr, sa, c.A0r);        // revolutions
    float v2 = fmaf(c.dVs, sb, c.V0s);
    float sn = __builtin_amdgcn_sinf(r);
    float cs = __builtin_amdgcn_cosf(r);
    return fmaf(v2, fmaf(x, sn, cs), x);
}

__device__ __forceinline__ float F3(float x, const MacCoef& c) {
    x = mac_step(x, c);
    x = mac_step(x, c);
    return mac_step(x, c);
}

// ---- prep kernel: LUT + tail slopes + packed weights, one launch ----------
__global__ __launch_bounds__(256) void prep_kernel(
    const float* __restrict__ angles, const float* __restrict__ velocity,
    const float* __restrict__ in_w,  const float* __restrict__ in_b,
    const float* __restrict__ out_w, const float* __restrict__ out_b,
    __half2* __restrict__ lut2, float* __restrict__ slopes,
    float4* __restrict__ wpack)
{
    const int b = blockIdx.x;
    if (b < 16) {
        int i = b * 256 + threadIdx.x;           // 0 .. 4095
        MacCoef c = make_coef(angles, velocity);
        float x0 = fmaf((float)i,       1.0f / LUT_SCALE, -LUT_B);
        float x1 = fmaf((float)(i + 1), 1.0f / LUT_SCALE, -LUT_B);
        lut2[i] = __halves2half2(__float2half(F3(x0, c)), __float2half(F3(x1, c)));
        if (i == 0) {
            // |x|>8 tails: sigmoids saturated -> F affine, slope cP^3/cN^3
            float snp = __builtin_amdgcn_sinf(c.A0r + c.dAr);
            float cP  = fmaf(c.V0s + c.dVs, snp, 1.0f);
            float snn = __builtin_amdgcn_sinf(c.A0r);
            float cN  = fmaf(c.V0s, snn, 1.0f);
            slopes[0] = cP * cP * cP;
            slopes[1] = cN * cN * cN;
        }
    } else {
        int s = (b - 16) * 256 + threadIdx.x;    // 0 .. 100351
        wpack[s] = make_float4(in_w[s], in_b[s], out_w[s], out_b[s]);
    }
}

// ------------- kernel 2: expansion -> LUT lerp -> gate -> sum4 -------------
__global__ __launch_bounds__(256, 8) void mac_kernel(
    const float* __restrict__ data,
    const float4* __restrict__ wpack,
    const float* __restrict__ slopes,
    const __half2* __restrict__ glut,
    float* __restrict__ out)
{
    __shared__ __half2 lut[LUT_N];               // 16 KB

    const int tid = threadIdx.x;
    // vectorized LDS fill: 4096 half2 = 1024 uint4
    {
        const uint4* src = (const uint4*)glut;
        uint4* dst = (uint4*)lut;
#pragma unroll
        for (int i = 0; i < 4; ++i) dst[tid + 256 * i] = src[tid + 256 * i];
    }

    const int t  = blockIdx.x * 256 + tid;       // 0 .. 12543 (= 256*49)
    const int os = t % 49;
    const int c  = t / 49;                       // data channel, 0..255

    // packed per-position weights for BOTH cc = 2c (e=0) and 2c+1 (e=1):
    // w[e][sf] = (iw, ib, ow, ob) at s = (2c)*196 + e*196 + sf*49 + os
    float4 w[2][4];
    {
        const float4* wq = wpack + c * 392 + os;
#pragma unroll
        for (int e = 0; e < 2; ++e)
#pragma unroll
            for (int sf = 0; sf < 4; ++sf)
                w[e][sf] = wq[e * 196 + sf * 49];
    }

    const float slopeP = slopes[0];
    const float slopeN = slopes[1];

    // front-load BOTH batches' data before the barrier (8 dwords in flight)
    const float* dptr = data + ((size_t)(blockIdx.y * BPT) * 256 + c) * 196 + os;
    float*       optr = out  + (size_t)(blockIdx.y * BPT) * 25088 + c * 98 + os;

    float rb[BPT][4];
#pragma unroll
    for (int k = 0; k < BPT; ++k)
#pragma unroll
        for (int sf = 0; sf < 4; ++sf) rb[k][sf] = dptr[(size_t)k * 50176 + sf * 49];

    __syncthreads();

#pragma unroll
    for (int k = 0; k < BPT; ++k) {
        float yv[2][4], tg[2][4];
#pragma unroll
        for (int sf = 0; sf < 4; ++sf) {
            float xv = rb[k][sf];
#pragma unroll
            for (int e = 0; e < 2; ++e) {
                float x0 = fmaf(xv, w[e][sf].x, w[e][sf].y);
                float xc = fminf(fmaxf(x0, -LUT_B), LUT_B);
                float fi = fmaf(xc, LUT_SCALE, 2048.0f);   // [0, 4096]
                int   j  = min((int)fi, LUT_N - 1);
                float fr = fi - (float)j;
                __half2 p = lut[j];                        // (F[j], F[j+1])
                float lo = __low2float(p), hi = __high2float(p);
                float v  = fmaf(fr, hi - lo, lo);          // interior F(x0)
                float dd = x0 - xc;                        // tails only
                float sl = x0 > 0.0f ? slopeP : slopeN;
                float y  = fmaf(dd, sl, v);
                yv[e][sf] = y;
                tg[e][sf] = fmaf(y, w[e][sf].z, w[e][sf].w);
            }
        }

        // gate att = 0.5*tg/(1+|tg|)+0.5, shared rcp per pair (exact)
#pragma unroll
        for (int e = 0; e < 2; ++e) {
            float acc = 0.0f;
#pragma unroll
            for (int p = 0; p < 2; ++p) {
                float t0 = tg[e][2 * p], t1 = tg[e][2 * p + 1];
                float d0 = 1.0f + fabsf(t0);
                float d1 = 1.0f + fabsf(t1);
                float rr = __builtin_amdgcn_rcpf(d0 * d1);
                acc = fmaf(yv[e][2 * p],     fmaf(0.5f * t0, d1 * rr, 0.5f), acc);
                acc = fmaf(yv[e][2 * p + 1], fmaf(0.5f * t1, d0 * rr, 0.5f), acc);
            }
            optr[(size_t)k * 25088 + e * 49] = acc;        // L2 write-combine
        }
    }
}

extern "C" void kernel_launch(void* const* d_in, const int* in_sizes, int n_in,
                              void* d_out, int out_size, void* d_ws, size_t ws_size,
                              hipStream_t stream) {
    const float* data   = (const float*)d_in[0];
    const float* in_w   = (const float*)d_in[1];
    const float* in_b   = (const float*)d_in[2];
    const float* out_w  = (const float*)d_in[3];
    const float* out_b  = (const float*)d_in[4];
    const float* angles = (const float*)d_in[5];
    const float* vel    = (const float*)d_in[6];
    float* out = (float*)d_out;

    __half2* lut    = (__half2*)d_ws;                          // 16 KB
    float*   slopes = (float*)((char*)d_ws + COEF_OFF);        // 2 floats
    float4*  wpack  = (float4*)((char*)d_ws + WPACK_OFF);      // 1.6 MB

    prep_kernel<<<dim3(16 + NWS / 256), 256, 0, stream>>>(
        angles, vel, in_w, in_b, out_w, out_b, lut, slopes, wpack);

    dim3 grid(49, 256 / BPT);                    // 49*128 blocks, (c,os) x batch
    mac_kernel<<<grid, 256, 0, stream>>>(data, wpack, slopes, lut, out);
}

// Round 5
// 118.158 us; speedup vs baseline: 1.0186x; 1.0072x over previous
//
#include <hip/hip_runtime.h>
#include <hip/hip_fp16.h>

// MacTensorUnit — R10. Structure (R4): x3 = F(x0) with F = f∘f∘f a UNIVERSAL
// scalar map -> prep kernel tabulates F (node-pair half2 entries on [-8,8]);
// kernel 2: expansion -> LDS-LUT lerp -> gate -> sum4. |x|>8: sigmoids
// saturate exactly in fp32 -> affine tails, slopes cP^3/cN^3 from runtime
// arrays.
//
// Kept: plain stores (R7), wpack float4 + precomputed slopes (R8),
//       BPT=2 with full data front-load before the barrier (R9).
// R10 (theory: remaining per-block serial cost = LDS LUT fill + barrier;
//      granularity direction validated by R9):
//  a) LUT_N 4096 -> 1024 (4 KB). Node-spacing lerp error h^2/8*|F''| ~ 3e-4,
//     subdominant to fp16 node quantization (~4e-3) that already dominates
//     absmax=0.125. Fill cost /4. FALSIFIER: absmax jump => revert to 4096.
//  b) blocks 256 -> 128 threads, __launch_bounds__(128,8): 16 blocks/CU
//     resident (32 waves unchanged), 2-wave barriers, 16 concurrent fills,
//     finer backfill granularity (R9's winning axis, one more step).

#define STEP2f    0.11110889f          // 0.33333^2
#define INV_2PI   0.15915494309189535f
#define LOG2E     1.4426950408889634f
#define LUT_N     1024
#define LUT_B     8.0f
#define LUT_SCALE 64.0f                // LUT_N / (2*LUT_B)
#define LUT_BIAS  512.0f               // LUT_N / 2
#define BPT       2                    // batches per thread (grid.y = 256/BPT)
#define TPB       128                  // threads per block (mac)
#define NWS       100352               // 512*196 weight positions
#define COEF_OFF  16384                // byte offset of slopes in d_ws
#define WPACK_OFF 32768                // byte offset of packed weights in d_ws

struct MacCoef {
    float ca1, ca3, cb1, cb3;   // logistic-Phi poly, -log2e folded
    float A0r, dAr;             // angle affine, revolutions
    float V0s, dVs;             // velocity affine * STEP^2
};

__device__ __forceinline__ MacCoef make_coef(const float* angles, const float* velocity) {
    MacCoef c;
    c.ca1 = -1.5957691216f * LOG2E;
    c.ca3 = -0.0713548168f * LOG2E;
    c.cb1 = c.ca1 * 1.41421356237f;
    c.cb3 = c.ca3 * 2.82842712475f;
    c.A0r = angles[0] * INV_2PI;
    c.dAr = (angles[4] - angles[0]) * 1.25f * INV_2PI;
    c.V0s = velocity[0] * STEP2f;
    c.dVs = (velocity[4] - velocity[0]) * 1.25f * STEP2f;
    return c;
}

// one exact MAC step (R3 math: 2 exp2 + shared rcp + hw sin/cos)
__device__ __forceinline__ float mac_step(float x, const MacCoef& c) {
    float xx = x * x;
    float ua = fminf(x * fmaf(c.ca3, xx, c.ca1), 60.0f);
    float ub = fminf(x * fmaf(c.cb3, xx, c.cb1), 60.0f);
    float ea = __builtin_amdgcn_exp2f(ua);
    float eb = __builtin_amdgcn_exp2f(ub);
    float da = 1.0f + ea, db = 1.0f + eb;
    float rp = __builtin_amdgcn_rcpf(da * db);
    float sa = db * rp;                       // ngd(x)
    float sb = da * rp;                       // nerf(x)
    float r  = fmaf(c.dAr, sa, c.A0r);        // revolutions
    float v2 = fmaf(c.dVs, sb, c.V0s);
    float sn = __builtin_amdgcn_sinf(r);
    float cs = __builtin_amdgcn_cosf(r);
    return fmaf(v2, fmaf(x, sn, cs), x);
}

__device__ __forceinline__ float F3(float x, const MacCoef& c) {
    x = mac_step(x, c);
    x = mac_step(x, c);
    return mac_step(x, c);
}

// ---- prep kernel: LUT + tail slopes + packed weights, one launch ----------
__global__ __launch_bounds__(256) void prep_kernel(
    const float* __restrict__ angles, const float* __restrict__ velocity,
    const float* __restrict__ in_w,  const float* __restrict__ in_b,
    const float* __restrict__ out_w, const float* __restrict__ out_b,
    __half2* __restrict__ lut2, float* __restrict__ slopes,
    float4* __restrict__ wpack)
{
    const int b = blockIdx.x;
    if (b < LUT_N / 256) {
        int i = b * 256 + threadIdx.x;           // 0 .. LUT_N-1
        MacCoef c = make_coef(angles, velocity);
        float x0 = fmaf((float)i,       1.0f / LUT_SCALE, -LUT_B);
        float x1 = fmaf((float)(i + 1), 1.0f / LUT_SCALE, -LUT_B);
        lut2[i] = __halves2half2(__float2half(F3(x0, c)), __float2half(F3(x1, c)));
        if (i == 0) {
            // |x|>8 tails: sigmoids saturated -> F affine, slope cP^3/cN^3
            float snp = __builtin_amdgcn_sinf(c.A0r + c.dAr);
            float cP  = fmaf(c.V0s + c.dVs, snp, 1.0f);
            float snn = __builtin_amdgcn_sinf(c.A0r);
            float cN  = fmaf(c.V0s, snn, 1.0f);
            slopes[0] = cP * cP * cP;
            slopes[1] = cN * cN * cN;
        }
    } else {
        int s = (b - LUT_N / 256) * 256 + threadIdx.x;   // 0 .. 100351
        wpack[s] = make_float4(in_w[s], in_b[s], out_w[s], out_b[s]);
    }
}

// ------------- kernel 2: expansion -> LUT lerp -> gate -> sum4 -------------
__global__ __launch_bounds__(TPB, 8) void mac_kernel(
    const float* __restrict__ data,
    const float4* __restrict__ wpack,
    const float* __restrict__ slopes,
    const __half2* __restrict__ glut,
    float* __restrict__ out)
{
    __shared__ __half2 lut[LUT_N];               // 4 KB

    const int tid = threadIdx.x;
    // vectorized LDS fill: 1024 half2 = 256 uint4, 2 per thread
    {
        const uint4* src = (const uint4*)glut;
        uint4* dst = (uint4*)lut;
#pragma unroll
        for (int i = 0; i < 2; ++i) dst[tid + TPB * i] = src[tid + TPB * i];
    }

    const int t  = blockIdx.x * TPB + tid;       // 0 .. 12543 (= 256*49)
    const int os = t % 49;
    const int c  = t / 49;                       // data channel, 0..255

    // packed per-position weights for BOTH cc = 2c (e=0) and 2c+1 (e=1):
    // w[e][sf] = (iw, ib, ow, ob) at s = (2c)*196 + e*196 + sf*49 + os
    float4 w[2][4];
    {
        const float4* wq = wpack + c * 392 + os;
#pragma unroll
        for (int e = 0; e < 2; ++e)
#pragma unroll
            for (int sf = 0; sf < 4; ++sf)
                w[e][sf] = wq[e * 196 + sf * 49];
    }

    const float slopeP = slopes[0];
    const float slopeN = slopes[1];

    // front-load BOTH batches' data before the barrier (8 dwords in flight)
    const float* dptr = data + ((size_t)(blockIdx.y * BPT) * 256 + c) * 196 + os;
    float*       optr = out  + (size_t)(blockIdx.y * BPT) * 25088 + c * 98 + os;

    float rb[BPT][4];
#pragma unroll
    for (int k = 0; k < BPT; ++k)
#pragma unroll
        for (int sf = 0; sf < 4; ++sf) rb[k][sf] = dptr[(size_t)k * 50176 + sf * 49];

    __syncthreads();

#pragma unroll
    for (int k = 0; k < BPT; ++k) {
        float yv[2][4], tg[2][4];
#pragma unroll
        for (int sf = 0; sf < 4; ++sf) {
            float xv = rb[k][sf];
#pragma unroll
            for (int e = 0; e < 2; ++e) {
                float x0 = fmaf(xv, w[e][sf].x, w[e][sf].y);
                float xc = fminf(fmaxf(x0, -LUT_B), LUT_B);
                float fi = fmaf(xc, LUT_SCALE, LUT_BIAS);  // [0, LUT_N]
                int   j  = min((int)fi, LUT_N - 1);
                float fr = fi - (float)j;
                __half2 p = lut[j];                        // (F[j], F[j+1])
                float lo = __low2float(p), hi = __high2float(p);
                float v  = fmaf(fr, hi - lo, lo);          // interior F(x0)
                float dd = x0 - xc;                        // tails only
                float sl = x0 > 0.0f ? slopeP : slopeN;
                float y  = fmaf(dd, sl, v);
                yv[e][sf] = y;
                tg[e][sf] = fmaf(y, w[e][sf].z, w[e][sf].w);
            }
        }

        // gate att = 0.5*tg/(1+|tg|)+0.5, shared rcp per pair (exact)
#pragma unroll
        for (int e = 0; e < 2; ++e) {
            float acc = 0.0f;
#pragma unroll
            for (int p = 0; p < 2; ++p) {
                float t0 = tg[e][2 * p], t1 = tg[e][2 * p + 1];
                float d0 = 1.0f + fabsf(t0);
                float d1 = 1.0f + fabsf(t1);
                float rr = __builtin_amdgcn_rcpf(d0 * d1);
                acc = fmaf(yv[e][2 * p],     fmaf(0.5f * t0, d1 * rr, 0.5f), acc);
                acc = fmaf(yv[e][2 * p + 1], fmaf(0.5f * t1, d0 * rr, 0.5f), acc);
            }
            optr[(size_t)k * 25088 + e * 49] = acc;        // L2 write-combine
        }
    }
}

extern "C" void kernel_launch(void* const* d_in, const int* in_sizes, int n_in,
                              void* d_out, int out_size, void* d_ws, size_t ws_size,
                              hipStream_t stream) {
    const float* data   = (const float*)d_in[0];
    const float* in_w   = (const float*)d_in[1];
    const float* in_b   = (const float*)d_in[2];
    const float* out_w  = (const float*)d_in[3];
    const float* out_b  = (const float*)d_in[4];
    const float* angles = (const float*)d_in[5];
    const float* vel    = (const float*)d_in[6];
    float* out = (float*)d_out;

    __half2* lut    = (__half2*)d_ws;                          // 2 KB used
    float*   slopes = (float*)((char*)d_ws + COEF_OFF);        // 2 floats
    float4*  wpack  = (float4*)((char*)d_ws + WPACK_OFF);      // 1.6 MB

    prep_kernel<<<dim3(LUT_N / 256 + NWS / 256), 256, 0, stream>>>(
        angles, vel, in_w, in_b, out_w, out_b, lut, slopes, wpack);

    dim3 grid(12544 / TPB, 256 / BPT);           // (c,os) x batch-chunks
    mac_kernel<<<grid, TPB, 0, stream>>>(data, wpack, slopes, lut, out);
}

// Round 6
// 116.648 us; speedup vs baseline: 1.0318x; 1.0129x over previous
//
#include <hip/hip_runtime.h>
#include <hip/hip_fp16.h>

// MacTensorUnit — R11. Structure (R4): x3 = F(x0) with F = f∘f∘f a UNIVERSAL
// scalar map -> prep kernel tabulates F (1024 node-pair half2 entries, [-8,8]);
// kernel 2: expansion -> LDS-LUT lerp -> gate -> sum4. |x|>8: sigmoids
// saturate exactly in fp32 -> affine tails, slopes cP^3/cN^3 from runtime
// arrays.
//
// Kept: plain stores (R7), wpack float4 + precomputed slopes (R8),
//       full data front-load before the barrier (R9), LUT_N=1024 + TPB=128
//       (R10; absmax stayed 0.125 -> fp16 node quantization dominates).
// R11 — the pre-registered A/B untangling R9's confound (granularity vs
// front-loading). Single variable vs R10: BPT 2 -> 4, full front-load.
//  * per-thread MLP doubles: 16 data dwords + 8 weight float4 + 2 LUT uint4
//    issued before any dependency (~26 VMEM in flight at block start).
//  * weight traffic (128 B/thread from L2) amortized over 2x output.
//  * cost: VGPR ~80 -> __launch_bounds__(128,6) -> 24 waves/CU (was 32).
// Pre-committed read: mac reappears in top-5 (>41us) => occupancy axis binds,
// revert to BPT=2 next round; mac stays invisible + dur ticks down => MLP
// axis binds, push deeper.

#define STEP2f    0.11110889f          // 0.33333^2
#define INV_2PI   0.15915494309189535f
#define LOG2E     1.4426950408889634f
#define LUT_N     1024
#define LUT_B     8.0f
#define LUT_SCALE 64.0f                // LUT_N / (2*LUT_B)
#define LUT_BIAS  512.0f               // LUT_N / 2
#define BPT       4                    // batches per thread (grid.y = 256/BPT)
#define TPB       128                  // threads per block (mac)
#define NWS       100352               // 512*196 weight positions
#define COEF_OFF  16384                // byte offset of slopes in d_ws
#define WPACK_OFF 32768                // byte offset of packed weights in d_ws

struct MacCoef {
    float ca1, ca3, cb1, cb3;   // logistic-Phi poly, -log2e folded
    float A0r, dAr;             // angle affine, revolutions
    float V0s, dVs;             // velocity affine * STEP^2
};

__device__ __forceinline__ MacCoef make_coef(const float* angles, const float* velocity) {
    MacCoef c;
    c.ca1 = -1.5957691216f * LOG2E;
    c.ca3 = -0.0713548168f * LOG2E;
    c.cb1 = c.ca1 * 1.41421356237f;
    c.cb3 = c.ca3 * 2.82842712475f;
    c.A0r = angles[0] * INV_2PI;
    c.dAr = (angles[4] - angles[0]) * 1.25f * INV_2PI;
    c.V0s = velocity[0] * STEP2f;
    c.dVs = (velocity[4] - velocity[0]) * 1.25f * STEP2f;
    return c;
}

// one exact MAC step (R3 math: 2 exp2 + shared rcp + hw sin/cos)
__device__ __forceinline__ float mac_step(float x, const MacCoef& c) {
    float xx = x * x;
    float ua = fminf(x * fmaf(c.ca3, xx, c.ca1), 60.0f);
    float ub = fminf(x * fmaf(c.cb3, xx, c.cb1), 60.0f);
    float ea = __builtin_amdgcn_exp2f(ua);
    float eb = __builtin_amdgcn_exp2f(ub);
    float da = 1.0f + ea, db = 1.0f + eb;
    float rp = __builtin_amdgcn_rcpf(da * db);
    float sa = db * rp;                       // ngd(x)
    float sb = da * rp;                       // nerf(x)
    float r  = fmaf(c.dAr, sa, c.A0r);        // revolutions
    float v2 = fmaf(c.dVs, sb, c.V0s);
    float sn = __builtin_amdgcn_sinf(r);
    float cs = __builtin_amdgcn_cosf(r);
    return fmaf(v2, fmaf(x, sn, cs), x);
}

__device__ __forceinline__ float F3(float x, const MacCoef& c) {
    x = mac_step(x, c);
    x = mac_step(x, c);
    return mac_step(x, c);
}

// ---- prep kernel: LUT + tail slopes + packed weights, one launch ----------
__global__ __launch_bounds__(256) void prep_kernel(
    const float* __restrict__ angles, const float* __restrict__ velocity,
    const float* __restrict__ in_w,  const float* __restrict__ in_b,
    const float* __restrict__ out_w, const float* __restrict__ out_b,
    __half2* __restrict__ lut2, float* __restrict__ slopes,
    float4* __restrict__ wpack)
{
    const int b = blockIdx.x;
    if (b < LUT_N / 256) {
        int i = b * 256 + threadIdx.x;           // 0 .. LUT_N-1
        MacCoef c = make_coef(angles, velocity);
        float x0 = fmaf((float)i,       1.0f / LUT_SCALE, -LUT_B);
        float x1 = fmaf((float)(i + 1), 1.0f / LUT_SCALE, -LUT_B);
        lut2[i] = __halves2half2(__float2half(F3(x0, c)), __float2half(F3(x1, c)));
        if (i == 0) {
            // |x|>8 tails: sigmoids saturated -> F affine, slope cP^3/cN^3
            float snp = __builtin_amdgcn_sinf(c.A0r + c.dAr);
            float cP  = fmaf(c.V0s + c.dVs, snp, 1.0f);
            float snn = __builtin_amdgcn_sinf(c.A0r);
            float cN  = fmaf(c.V0s, snn, 1.0f);
            slopes[0] = cP * cP * cP;
            slopes[1] = cN * cN * cN;
        }
    } else {
        int s = (b - LUT_N / 256) * 256 + threadIdx.x;   // 0 .. 100351
        wpack[s] = make_float4(in_w[s], in_b[s], out_w[s], out_b[s]);
    }
}

// ------------- kernel 2: expansion -> LUT lerp -> gate -> sum4 -------------
__global__ __launch_bounds__(TPB, 6) void mac_kernel(
    const float* __restrict__ data,
    const float4* __restrict__ wpack,
    const float* __restrict__ slopes,
    const __half2* __restrict__ glut,
    float* __restrict__ out)
{
    __shared__ __half2 lut[LUT_N];               // 4 KB

    const int tid = threadIdx.x;

    const int t  = blockIdx.x * TPB + tid;       // 0 .. 12543 (= 256*49)
    const int os = t % 49;
    const int c  = t / 49;                       // data channel, 0..255

    // front-load ALL batches' data first (16 dwords, HBM -> longest latency)
    const float* dptr = data + ((size_t)(blockIdx.y * BPT) * 256 + c) * 196 + os;
    float*       optr = out  + (size_t)(blockIdx.y * BPT) * 25088 + c * 98 + os;

    float rb[BPT][4];
#pragma unroll
    for (int k = 0; k < BPT; ++k)
#pragma unroll
        for (int sf = 0; sf < 4; ++sf) rb[k][sf] = dptr[(size_t)k * 50176 + sf * 49];

    // packed per-position weights for BOTH cc = 2c (e=0) and 2c+1 (e=1):
    // w[e][sf] = (iw, ib, ow, ob) at s = (2c)*196 + e*196 + sf*49 + os
    float4 w[2][4];
    {
        const float4* wq = wpack + c * 392 + os;
#pragma unroll
        for (int e = 0; e < 2; ++e)
#pragma unroll
            for (int sf = 0; sf < 4; ++sf)
                w[e][sf] = wq[e * 196 + sf * 49];
    }

    // vectorized LDS fill: 1024 half2 = 256 uint4, 2 per thread (L2-hot)
    {
        const uint4* src = (const uint4*)glut;
        uint4* dst = (uint4*)lut;
#pragma unroll
        for (int i = 0; i < 2; ++i) dst[tid + TPB * i] = src[tid + TPB * i];
    }

    const float slopeP = slopes[0];
    const float slopeN = slopes[1];

    __syncthreads();

#pragma unroll
    for (int k = 0; k < BPT; ++k) {
        float yv[2][4], tg[2][4];
#pragma unroll
        for (int sf = 0; sf < 4; ++sf) {
            float xv = rb[k][sf];
#pragma unroll
            for (int e = 0; e < 2; ++e) {
                float x0 = fmaf(xv, w[e][sf].x, w[e][sf].y);
                float xc = fminf(fmaxf(x0, -LUT_B), LUT_B);
                float fi = fmaf(xc, LUT_SCALE, LUT_BIAS);  // [0, LUT_N]
                int   j  = min((int)fi, LUT_N - 1);
                float fr = fi - (float)j;
                __half2 p = lut[j];                        // (F[j], F[j+1])
                float lo = __low2float(p), hi = __high2float(p);
                float v  = fmaf(fr, hi - lo, lo);          // interior F(x0)
                float dd = x0 - xc;                        // tails only
                float sl = x0 > 0.0f ? slopeP : slopeN;
                float y  = fmaf(dd, sl, v);
                yv[e][sf] = y;
                tg[e][sf] = fmaf(y, w[e][sf].z, w[e][sf].w);
            }
        }

        // gate att = 0.5*tg/(1+|tg|)+0.5, shared rcp per pair (exact)
#pragma unroll
        for (int e = 0; e < 2; ++e) {
            float acc = 0.0f;
#pragma unroll
            for (int p = 0; p < 2; ++p) {
                float t0 = tg[e][2 * p], t1 = tg[e][2 * p + 1];
                float d0 = 1.0f + fabsf(t0);
                float d1 = 1.0f + fabsf(t1);
                float rr = __builtin_amdgcn_rcpf(d0 * d1);
                acc = fmaf(yv[e][2 * p],     fmaf(0.5f * t0, d1 * rr, 0.5f), acc);
                acc = fmaf(yv[e][2 * p + 1], fmaf(0.5f * t1, d0 * rr, 0.5f), acc);
            }
            optr[(size_t)k * 25088 + e * 49] = acc;        // L2 write-combine
        }
    }
}

extern "C" void kernel_launch(void* const* d_in, const int* in_sizes, int n_in,
                              void* d_out, int out_size, void* d_ws, size_t ws_size,
                              hipStream_t stream) {
    const float* data   = (const float*)d_in[0];
    const float* in_w   = (const float*)d_in[1];
    const float* in_b   = (const float*)d_in[2];
    const float* out_w  = (const float*)d_in[3];
    const float* out_b  = (const float*)d_in[4];
    const float* angles = (const float*)d_in[5];
    const float* vel    = (const float*)d_in[6];
    float* out = (float*)d_out;

    __half2* lut    = (__half2*)d_ws;                          // 2 KB used
    float*   slopes = (float*)((char*)d_ws + COEF_OFF);        // 2 floats
    float4*  wpack  = (float4*)((char*)d_ws + WPACK_OFF);      // 1.6 MB

    prep_kernel<<<dim3(LUT_N / 256 + NWS / 256), 256, 0, stream>>>(
        angles, vel, in_w, in_b, out_w, out_b, lut, slopes, wpack);

    dim3 grid(12544 / TPB, 256 / BPT);           // (c,os) x batch-chunks
    mac_kernel<<<grid, TPB, 0, stream>>>(data, wpack, slopes, lut, out);
}

// Round 7
// 115.465 us; speedup vs baseline: 1.0424x; 1.0102x over previous
//
#include <hip/hip_runtime.h>
#include <hip/hip_fp16.h>

// MacTensorUnit — R12. Structure (R4): x3 = F(x0) with F = f∘f∘f a UNIVERSAL
// scalar map -> prep kernel tabulates F (1024 node-pair half2 entries, [-8,8]);
// kernel 2: expansion -> LDS-LUT lerp -> gate -> sum4. |x|>8: sigmoids
// saturate exactly in fp32 -> affine tails, slopes cP^3/cN^3 from runtime
// arrays.
//
// Kept: plain stores (R7), wpack float4 + precomputed slopes (R8),
//       full data front-load before any use (R9/R11), LUT_N=1024 + TPB=128
//       (R10).
// R11 A/B resolved: BPT 2->4 at 24 waves/CU did NOT regress -> occupancy
// axis is slack; front-loading/MLP + setup amortization is the live axis.
// R12 (single variable): BPT 4 -> 8, __launch_bounds__(128,4).
//  * 42 independent VMEM ops in flight per thread before any dependency
//    (2 LUT uint4 first -> pre-barrier vmcnt drains only those, 40 data/
//    weight loads stay in flight across the barrier).
//  * weight/LUT/setup cost amortized over 8 batches (1568 blocks, 2 waves).
//  * cost: 16 waves/CU (VGPR cap 128). Pre-committed read: mac in top-5
//    (>=42us) => occupancy/VGPR regression, revert to BPT=4 next round;
//    invisible + dur down => MLP axis still paying.

#define STEP2f    0.11110889f          // 0.33333^2
#define INV_2PI   0.15915494309189535f
#define LOG2E     1.4426950408889634f
#define LUT_N     1024
#define LUT_B     8.0f
#define LUT_SCALE 64.0f                // LUT_N / (2*LUT_B)
#define LUT_BIAS  512.0f               // LUT_N / 2
#define BPT       8                    // batches per thread (grid.y = 256/BPT)
#define TPB       128                  // threads per block (mac)
#define NWS       100352               // 512*196 weight positions
#define COEF_OFF  16384                // byte offset of slopes in d_ws
#define WPACK_OFF 32768                // byte offset of packed weights in d_ws

struct MacCoef {
    float ca1, ca3, cb1, cb3;   // logistic-Phi poly, -log2e folded
    float A0r, dAr;             // angle affine, revolutions
    float V0s, dVs;             // velocity affine * STEP^2
};

__device__ __forceinline__ MacCoef make_coef(const float* angles, const float* velocity) {
    MacCoef c;
    c.ca1 = -1.5957691216f * LOG2E;
    c.ca3 = -0.0713548168f * LOG2E;
    c.cb1 = c.ca1 * 1.41421356237f;
    c.cb3 = c.ca3 * 2.82842712475f;
    c.A0r = angles[0] * INV_2PI;
    c.dAr = (angles[4] - angles[0]) * 1.25f * INV_2PI;
    c.V0s = velocity[0] * STEP2f;
    c.dVs = (velocity[4] - velocity[0]) * 1.25f * STEP2f;
    return c;
}

// one exact MAC step (R3 math: 2 exp2 + shared rcp + hw sin/cos)
__device__ __forceinline__ float mac_step(float x, const MacCoef& c) {
    float xx = x * x;
    float ua = fminf(x * fmaf(c.ca3, xx, c.ca1), 60.0f);
    float ub = fminf(x * fmaf(c.cb3, xx, c.cb1), 60.0f);
    float ea = __builtin_amdgcn_exp2f(ua);
    float eb = __builtin_amdgcn_exp2f(ub);
    float da = 1.0f + ea, db = 1.0f + eb;
    float rp = __builtin_amdgcn_rcpf(da * db);
    float sa = db * rp;                       // ngd(x)
    float sb = da * rp;                       // nerf(x)
    float r  = fmaf(c.dAr, sa, c.A0r);        // revolutions
    float v2 = fmaf(c.dVs, sb, c.V0s);
    float sn = __builtin_amdgcn_sinf(r);
    float cs = __builtin_amdgcn_cosf(r);
    return fmaf(v2, fmaf(x, sn, cs), x);
}

__device__ __forceinline__ float F3(float x, const MacCoef& c) {
    x = mac_step(x, c);
    x = mac_step(x, c);
    return mac_step(x, c);
}

// ---- prep kernel: LUT + tail slopes + packed weights, one launch ----------
__global__ __launch_bounds__(256) void prep_kernel(
    const float* __restrict__ angles, const float* __restrict__ velocity,
    const float* __restrict__ in_w,  const float* __restrict__ in_b,
    const float* __restrict__ out_w, const float* __restrict__ out_b,
    __half2* __restrict__ lut2, float* __restrict__ slopes,
    float4* __restrict__ wpack)
{
    const int b = blockIdx.x;
    if (b < LUT_N / 256) {
        int i = b * 256 + threadIdx.x;           // 0 .. LUT_N-1
        MacCoef c = make_coef(angles, velocity);
        float x0 = fmaf((float)i,       1.0f / LUT_SCALE, -LUT_B);
        float x1 = fmaf((float)(i + 1), 1.0f / LUT_SCALE, -LUT_B);
        lut2[i] = __halves2half2(__float2half(F3(x0, c)), __float2half(F3(x1, c)));
        if (i == 0) {
            // |x|>8 tails: sigmoids saturated -> F affine, slope cP^3/cN^3
            float snp = __builtin_amdgcn_sinf(c.A0r + c.dAr);
            float cP  = fmaf(c.V0s + c.dVs, snp, 1.0f);
            float snn = __builtin_amdgcn_sinf(c.A0r);
            float cN  = fmaf(c.V0s, snn, 1.0f);
            slopes[0] = cP * cP * cP;
            slopes[1] = cN * cN * cN;
        }
    } else {
        int s = (b - LUT_N / 256) * 256 + threadIdx.x;   // 0 .. 100351
        wpack[s] = make_float4(in_w[s], in_b[s], out_w[s], out_b[s]);
    }
}

// ------------- kernel 2: expansion -> LUT lerp -> gate -> sum4 -------------
__global__ __launch_bounds__(TPB, 4) void mac_kernel(
    const float* __restrict__ data,
    const float4* __restrict__ wpack,
    const float* __restrict__ slopes,
    const __half2* __restrict__ glut,
    float* __restrict__ out)
{
    __shared__ __half2 lut[LUT_N];               // 4 KB

    const int tid = threadIdx.x;

    const int t  = blockIdx.x * TPB + tid;       // 0 .. 12543 (= 256*49)
    const int os = t % 49;
    const int c  = t / 49;                       // data channel, 0..255

    // LUT loads FIRST: pre-barrier vmcnt drains only these two (in-order
    // vmcnt retirement), the 40 later loads stay in flight across the barrier
    uint4 lv0, lv1;
    {
        const uint4* src = (const uint4*)glut;
        lv0 = src[tid];
        lv1 = src[tid + TPB];
    }

    // front-load ALL batches' data (32 dwords, HBM -> longest latency)
    const float* dptr = data + ((size_t)(blockIdx.y * BPT) * 256 + c) * 196 + os;
    float*       optr = out  + (size_t)(blockIdx.y * BPT) * 25088 + c * 98 + os;

    float rb[BPT][4];
#pragma unroll
    for (int k = 0; k < BPT; ++k)
#pragma unroll
        for (int sf = 0; sf < 4; ++sf) rb[k][sf] = dptr[(size_t)k * 50176 + sf * 49];

    // packed per-position weights for BOTH cc = 2c (e=0) and 2c+1 (e=1):
    // w[e][sf] = (iw, ib, ow, ob) at s = (2c)*196 + e*196 + sf*49 + os
    float4 w[2][4];
    {
        const float4* wq = wpack + c * 392 + os;
#pragma unroll
        for (int e = 0; e < 2; ++e)
#pragma unroll
            for (int sf = 0; sf < 4; ++sf)
                w[e][sf] = wq[e * 196 + sf * 49];
    }

    // LDS fill from the two prefetched uint4
    {
        uint4* dst = (uint4*)lut;
        dst[tid]       = lv0;
        dst[tid + TPB] = lv1;
    }

    const float slopeP = slopes[0];
    const float slopeN = slopes[1];

    __syncthreads();

#pragma unroll
    for (int k = 0; k < BPT; ++k) {
        float yv[2][4], tg[2][4];
#pragma unroll
        for (int sf = 0; sf < 4; ++sf) {
            float xv = rb[k][sf];
#pragma unroll
            for (int e = 0; e < 2; ++e) {
                float x0 = fmaf(xv, w[e][sf].x, w[e][sf].y);
                float xc = fminf(fmaxf(x0, -LUT_B), LUT_B);
                float fi = fmaf(xc, LUT_SCALE, LUT_BIAS);  // [0, LUT_N]
                int   j  = min((int)fi, LUT_N - 1);
                float fr = fi - (float)j;
                __half2 p = lut[j];                        // (F[j], F[j+1])
                float lo = __low2float(p), hi = __high2float(p);
                float v  = fmaf(fr, hi - lo, lo);          // interior F(x0)
                float dd = x0 - xc;                        // tails only
                float sl = x0 > 0.0f ? slopeP : slopeN;
                float y  = fmaf(dd, sl, v);
                yv[e][sf] = y;
                tg[e][sf] = fmaf(y, w[e][sf].z, w[e][sf].w);
            }
        }

        // gate att = 0.5*tg/(1+|tg|)+0.5, shared rcp per pair (exact)
#pragma unroll
        for (int e = 0; e < 2; ++e) {
            float acc = 0.0f;
#pragma unroll
            for (int p = 0; p < 2; ++p) {
                float t0 = tg[e][2 * p], t1 = tg[e][2 * p + 1];
                float d0 = 1.0f + fabsf(t0);
                float d1 = 1.0f + fabsf(t1);
                float rr = __builtin_amdgcn_rcpf(d0 * d1);
                acc = fmaf(yv[e][2 * p],     fmaf(0.5f * t0, d1 * rr, 0.5f), acc);
                acc = fmaf(yv[e][2 * p + 1], fmaf(0.5f * t1, d0 * rr, 0.5f), acc);
            }
            optr[(size_t)k * 25088 + e * 49] = acc;        // L2 write-combine
        }
    }
}

extern "C" void kernel_launch(void* const* d_in, const int* in_sizes, int n_in,
                              void* d_out, int out_size, void* d_ws, size_t ws_size,
                              hipStream_t stream) {
    const float* data   = (const float*)d_in[0];
    const float* in_w   = (const float*)d_in[1];
    const float* in_b   = (const float*)d_in[2];
    const float* out_w  = (const float*)d_in[3];
    const float* out_b  = (const float*)d_in[4];
    const float* angles = (const float*)d_in[5];
    const float* vel    = (const float*)d_in[6];
    float* out = (float*)d_out;

    __half2* lut    = (__half2*)d_ws;                          // 4 KB used
    float*   slopes = (float*)((char*)d_ws + COEF_OFF);        // 2 floats
    float4*  wpack  = (float4*)((char*)d_ws + WPACK_OFF);      // 1.6 MB

    prep_kernel<<<dim3(LUT_N / 256 + NWS / 256), 256, 0, stream>>>(
        angles, vel, in_w, in_b, out_w, out_b, lut, slopes, wpack);

    dim3 grid(12544 / TPB, 256 / BPT);           // (c,os) x batch-chunks
    mac_kernel<<<grid, TPB, 0, stream>>>(data, wpack, slopes, lut, out);
}